// Round 3
// baseline (282.129 us; speedup 1.0000x reference)
//
#include <hip/hip_runtime.h>
#include <hip/hip_bf16.h>
#include <hip/hip_cooperative_groups.h>

namespace cg = cooperative_groups;

// BahdanauAttention on MI355X (gfx950). ALL float I/O is fp32.
// Internal compute uses bf16 MFMA (no fp32 MFMA on CDNA4).
// R18: single cooperative mega-kernel, 5 phases with grid.sync() between.
// Phase bodies are the proven R16 kernels (K2 reverted to v6 scalar —
// R17 lesson: v_pk_fma_f32 gives NO throughput on CDNA4; 157 TF fp32 peak
// is already reachable with scalar v_fma, packed is density only).
//  P0: cast fp32->bf16 (grid-stride)
//  P1: EA = exp(2*(q @ Ws^T)), EBT = exp(2*(enc @ Wh^T))^T  [gload_lds GEMM]
//  P2: energies E = sum_h (-2v_h)/(1+EA*EB)   [v6 scalar, VALU-bound]
//  P3: softmax + ctx GEMM (fused)
//  P4: out = tanh([ctx|q] @ Wout^T)
// Fallback: if hipLaunchCooperativeKernel errors (capture-unsupported),
// launch the 5-kernel pipeline instead (identical math).
// d_ws is 256 MiB; harness 0xAA fill (~45 us) is a fixed serialized cost.

typedef __attribute__((ext_vector_type(8))) short bf16x8;
typedef __attribute__((ext_vector_type(4))) float floatx4;

#define C2LOG2E 2.8853900817779268f   // 2*log2(e)
#define LOG2E   1.4426950408889634f
#define NEGBIG  -1e30f
#define TQ 4

__device__ __forceinline__ float fexp2(float x) { return __builtin_amdgcn_exp2f(x); }
__device__ __forceinline__ float frcp(float x)  { return __builtin_amdgcn_rcpf(x); }
__device__ __forceinline__ float ftanh(float x) {
    return 1.0f - 2.0f * frcp(1.0f + fexp2(C2LOG2E * x));
}
__device__ __forceinline__ float fexp2x(float x) {   // e^{2x}
    return fexp2(C2LOG2E * x);
}

__device__ __forceinline__ unsigned int f2bf_bits(float f) {
    unsigned int u = __float_as_uint(f);
    return (u + 0x7fffu + ((u >> 16) & 1u)) >> 16;   // RNE (inputs finite)
}

// async 16B global->LDS (wave-cooperative: lane i writes ldsbase + i*16)
typedef const __attribute__((address_space(1))) unsigned int* gas_u32p;
typedef __attribute__((address_space(3))) unsigned int* las_u32p;
__device__ __forceinline__ void gload16(const void* g, void* l) {
    __builtin_amdgcn_global_load_lds((gas_u32p)g, (las_u32p)l, 16, 0, 0);
}

__device__ __forceinline__ void cast_range(const float* __restrict__ s,
                                           unsigned short* __restrict__ d,
                                           int n4, int gtid, int gs)
{
    for (int i = gtid; i < n4; i += gs) {
        float4 f = ((const float4*)s)[i];
        ushort4 o;
        o.x = (unsigned short)f2bf_bits(f.x);
        o.y = (unsigned short)f2bf_bits(f.y);
        o.z = (unsigned short)f2bf_bits(f.z);
        o.w = (unsigned short)f2bf_bits(f.w);
        ((ushort4*)d)[i] = o;
    }
}

// ============================ MEGA KERNEL ====================================
__global__ __launch_bounds__(512, 4) void bahdanau_mega(
    const float* __restrict__ q, const float* __restrict__ e,
    const int* __restrict__ Len, const float* __restrict__ Ws,
    const float* __restrict__ Wh, const float* __restrict__ Vv,
    const float* __restrict__ Wout, float* __restrict__ Out,
    float* __restrict__ EA, float* __restrict__ EBT, float* __restrict__ E,
    unsigned short* __restrict__ qb, unsigned short* __restrict__ eb,
    unsigned short* __restrict__ Wsb, unsigned short* __restrict__ Whb,
    unsigned short* __restrict__ Wob, unsigned short* __restrict__ ctx)
{
    cg::grid_group grid = cg::this_grid();
    __shared__ __align__(16) char smem[67584];   // union across phases

    const int rb = blockIdx.x, G = gridDim.x;
    const int tid = threadIdx.x, lane = tid & 63, w = tid >> 6;

    // -------- P0: casts (grid-stride float4) --------
    {
        int gtid = rb * 512 + tid, gs = G * 512;
        cast_range(q,   qb,  262144, gtid, gs);
        cast_range(e,   eb,  262144, gtid, gs);
        cast_range(Ws,  Wsb,  65536, gtid, gs);
        cast_range(Wh,  Whb,  65536, gtid, gs);
        cast_range(Wout,Wob, 131072, gtid, gs);
    }
    grid.sync();

    // -------- P1: dual 32x64 GEMM + exp (2 concurrent 4-wave groups) --------
    {
        int g = w >> 2, wl = w & 3;
        unsigned short* sAg = (unsigned short*)(smem + g * 12288);
        unsigned short* sBg = (unsigned short*)(smem + g * 12288 + 4096);
        for (int vb = rb * 2 + g; vb < 1024; vb += G * 2) {
            __syncthreads();                     // LDS reuse guard
            int blk = vb;
            const unsigned short *X, *W; float* C; int mt, nt, N;
            if (blk < 512) { X = qb; W = Wsb; C = EA; N = 512;  mt = blk >> 3; nt = blk & 7; }
            else { blk -= 512; X = Whb; W = eb; C = EBT; N = 2048; mt = blk >> 5; nt = blk & 31; }
            int row0 = mt * 32, col0 = nt * 64;
            int mw = (wl & 1) * 16, nw = (wl >> 1) * 32;
            int r = lane & 15;
            int lr  = lane >> 3;
            int csw = ((lane & 7) ^ lr) << 3;    // swizzled col (shorts)
            const unsigned short* gA  = X + (size_t)(row0 + 8 * wl + lr) * 512 + csw;
            const unsigned short* gB0 = W + (size_t)(col0 + 16 * wl + lr) * 512 + csw;
            const unsigned short* gB1 = W + (size_t)(col0 + 16 * wl + 8 + lr) * 512 + csw;
            unsigned short* lA  = sAg + wl * 512;
            unsigned short* lB0 = sBg + wl * 1024;
            unsigned short* lB1 = sBg + wl * 1024 + 512;
            int xr = (r & 7) << 4;
            int cq = (lane >> 4) << 4;
            const char* cA = (const char*)sAg;
            const char* cB = (const char*)sBg;
            int a0 = (mw + r) * 128 + (cq ^ xr);
            int a1 = (mw + r) * 128 + ((cq + 64) ^ xr);
            int b0 = (nw + r) * 128 + (cq ^ xr);
            int b1 = (nw + r) * 128 + ((cq + 64) ^ xr);

            floatx4 acc0 = {0,0,0,0}, acc1 = {0,0,0,0};
            gload16(gA, lA); gload16(gB0, lB0); gload16(gB1, lB1);

            for (int kb = 0; kb < 8; ++kb) {
                __syncthreads();                 // drains vmcnt -> tile ready
                bf16x8 af0 = *(const bf16x8*)(cA + a0);
                bf16x8 af1 = *(const bf16x8*)(cA + a1);
                bf16x8 b00 = *(const bf16x8*)(cB + b0);
                bf16x8 b10 = *(const bf16x8*)(cB + b0 + 2048);
                bf16x8 b01 = *(const bf16x8*)(cB + b1);
                bf16x8 b11 = *(const bf16x8*)(cB + b1 + 2048);
                acc0 = __builtin_amdgcn_mfma_f32_16x16x32_bf16(af0, b00, acc0, 0, 0, 0);
                acc1 = __builtin_amdgcn_mfma_f32_16x16x32_bf16(af0, b10, acc1, 0, 0, 0);
                acc0 = __builtin_amdgcn_mfma_f32_16x16x32_bf16(af1, b01, acc0, 0, 0, 0);
                acc1 = __builtin_amdgcn_mfma_f32_16x16x32_bf16(af1, b11, acc1, 0, 0, 0);
                if (kb < 7) {
                    __syncthreads();
                    gA += 64; gB0 += 64; gB1 += 64;
                    gload16(gA, lA); gload16(gB0, lB0); gload16(gB1, lB1);
                }
            }
            int rq = (lane >> 4) * 4;
            float* cp = C + (size_t)(row0 + mw + rq) * N + col0 + nw + r;
#pragma unroll
            for (int i = 0; i < 4; ++i) {
                cp[(size_t)i * N]      = fexp2x(acc0[i]);
                cp[(size_t)i * N + 16] = fexp2x(acc1[i]);
            }
        }
    }
    grid.sync();

    // -------- P2: energies (v6 scalar) --------
    {
        float (*sA)[516] = (float(*)[516])smem;           // 8256 B
        float* sWn = (float*)(smem + 8256);               // 2048 B
        float (*sRed)[TQ][130] = (float(*)[TQ][130])(smem + 10304); // 16640 B
        for (int vb = rb; vb < 1024; vb += G) {
            int b  = vb >> 7;
            int j  = (vb >> 6) & 1;
            int tq = vb & 63;
            int len = Len[b];
            if (j * 128 >= len) continue;      // block-uniform skip
            int row0g = b * 256 + tq * TQ;

            {   // stage EA rows (4 x 512 fp32) and wn
                int t = tid >> 7, c = (tid & 127) * 4;
                *(float4*)&sA[t][c] = *(const float4*)(EA + (size_t)(row0g + t) * 512 + c);
                sWn[tid] = -2.0f * Vv[tid];
            }
            __syncthreads();

            int h0 = w * 64;
            float acc[TQ][2] = {{0.f}};
            const float* bt = EBT + (size_t)h0 * 2048 + b * 256 + j * 128 + lane;

            float B[8], P[8];
#pragma unroll
            for (int i = 0; i < 4; ++i) {
                B[i]     = bt[(size_t)i * 2048];
                B[i + 4] = bt[(size_t)i * 2048 + 64];
            }
#pragma unroll
            for (int hh = 0; hh < 64; hh += 4) {
                if (hh + 4 < 64) {
                    const float* nb = bt + (size_t)(hh + 4) * 2048;
#pragma unroll
                    for (int i = 0; i < 4; ++i) {
                        P[i]     = nb[(size_t)i * 2048];
                        P[i + 4] = nb[(size_t)i * 2048 + 64];
                    }
                }
                float4 w4 = *(const float4*)&sWn[h0 + hh];
#pragma unroll
                for (int t = 0; t < TQ; ++t) {
                    float4 a4 = *(const float4*)&sA[t][h0 + hh];
#pragma unroll
                    for (int u = 0; u < 2; ++u) {
                        float d0 = fmaf(a4.x, B[4 * u + 0], 1.0f);
                        float d1 = fmaf(a4.y, B[4 * u + 1], 1.0f);
                        float d2 = fmaf(a4.z, B[4 * u + 2], 1.0f);
                        float d3 = fmaf(a4.w, B[4 * u + 3], 1.0f);
                        float num01 = fmaf(w4.x, d1, w4.y * d0);
                        float num23 = fmaf(w4.z, d3, w4.w * d2);
                        acc[t][u] = fmaf(num01, frcp(d0 * d1), acc[t][u]);
                        acc[t][u] = fmaf(num23, frcp(d2 * d3), acc[t][u]);
                    }
                }
#pragma unroll
                for (int i = 0; i < 8; ++i) B[i] = P[i];
            }

#pragma unroll
            for (int t = 0; t < TQ; ++t) {
                sRed[w][t][lane]      = acc[t][0];
                sRed[w][t][lane + 64] = acc[t][1];
            }
            __syncthreads();
            {
                int t = tid >> 7, s = tid & 127;
                float sum = 0.f;
#pragma unroll
                for (int ww = 0; ww < 8; ++ww) sum += sRed[ww][t][s];
                E[(size_t)(row0g + t) * 256 + j * 128 + s] = sum;
            }
        }
    }
    grid.sync();

    // -------- P3: fused softmax + ctx GEMM --------
    {
        unsigned short (*EncT)[264] = (unsigned short(*)[264])smem;          // 33792 B
        unsigned short (*sWb)[264]  = (unsigned short(*)[264])(smem + 33792);
        for (int vb = rb; vb < 256; vb += G) {
            __syncthreads();
            int b = vb & 7, hq = (vb >> 3) & 7, tg = vb >> 6;
            int len = Len[b];

            {   // stage + transpose enc tile
                int s = tid >> 1, hg = (tid & 1) * 32;
                const ushort4* src = (const ushort4*)(eb + (size_t)(b * 256 + s) * 512 + hq * 64 + hg);
#pragma unroll
                for (int k = 0; k < 8; ++k) {
                    ushort4 u = src[k];
                    EncT[hg + k * 4 + 0][s] = u.x;
                    EncT[hg + k * 4 + 1][s] = u.y;
                    EncT[hg + k * 4 + 2][s] = u.z;
                    EncT[hg + k * 4 + 3][s] = u.w;
                }
            }
            for (int i = 0; i < 8; ++i) {
                int row = w * 8 + i;
                const float* erow = E + (size_t)(b * 256 + tg * 64 + row) * 256;
                float ev[4];
#pragma unroll
                for (int jj = 0; jj < 4; ++jj) {
                    int s = lane + 64 * jj;
                    ev[jj] = (s < len) ? erow[s] : NEGBIG;
                }
                float m = fmaxf(fmaxf(ev[0], ev[1]), fmaxf(ev[2], ev[3]));
#pragma unroll
                for (int o = 1; o < 64; o <<= 1) m = fmaxf(m, __shfl_xor(m, o, 64));
                float wv[4], wsum = 0.f;
#pragma unroll
                for (int jj = 0; jj < 4; ++jj) { wv[jj] = fexp2((ev[jj] - m) * LOG2E); wsum += wv[jj]; }
#pragma unroll
                for (int o = 1; o < 64; o <<= 1) wsum += __shfl_xor(wsum, o, 64);
                float inv = frcp(wsum);
#pragma unroll
                for (int jj = 0; jj < 4; ++jj)
                    sWb[row][lane + 64 * jj] = (unsigned short)f2bf_bits(wv[jj] * inv);
            }
            __syncthreads();

            int mt = w & 3, npair = w >> 2;
            int t0 = mt * 16;
            int r  = lane & 15, kq = (lane >> 4) * 8;
            int n0 = npair * 32 + r;
            floatx4 acc0 = {0.f,0.f,0.f,0.f}, acc1 = {0.f,0.f,0.f,0.f};
#pragma unroll
            for (int k = 0; k < 8; ++k) {
                bf16x8 a  = *(const bf16x8*)(&sWb[t0 + r][kq + 32 * k]);
                bf16x8 b0 = *(const bf16x8*)(&EncT[n0][kq + 32 * k]);
                bf16x8 b1 = *(const bf16x8*)(&EncT[n0 + 16][kq + 32 * k]);
                acc0 = __builtin_amdgcn_mfma_f32_16x16x32_bf16(a, b0, acc0, 0, 0, 0);
                acc1 = __builtin_amdgcn_mfma_f32_16x16x32_bf16(a, b1, acc1, 0, 0, 0);
            }
            int row0 = (lane >> 4) * 4;
            unsigned short* op = ctx + (size_t)(b * 256 + tg * 64 + t0 + row0) * 512 + hq * 64 + npair * 32 + r;
#pragma unroll
            for (int i = 0; i < 4; ++i) {
                op[i * 512]      = (unsigned short)f2bf_bits(acc0[i]);
                op[i * 512 + 16] = (unsigned short)f2bf_bits(acc1[i]);
            }
        }
    }
    grid.sync();

    // -------- P4: out = tanh([ctx|q] @ Wout^T) --------
    {
        int g = w >> 2, wl = w & 3;
        unsigned short* sAg = (unsigned short*)(smem + g * 12288);
        unsigned short* sBg = (unsigned short*)(smem + g * 12288 + 4096);
        for (int vb = rb * 2 + g; vb < 512; vb += G * 2) {
            __syncthreads();
            int mt = vb >> 3, nt = vb & 7;
            int row0 = mt * 32, col0 = nt * 64;
            int mw = (wl & 1) * 16, nw = (wl >> 1) * 32;
            int r = lane & 15;
            int lr  = lane >> 3;
            int csw = ((lane & 7) ^ lr) << 3;
            const unsigned short* gactx = ctx + (size_t)(row0 + 8 * wl + lr) * 512 + csw;
            const unsigned short* gaq   = qb  + (size_t)(row0 + 8 * wl + lr) * 512 + csw;
            const unsigned short* gB0   = Wob + (size_t)(col0 + 16 * wl + lr) * 1024 + csw;
            const unsigned short* gB1   = Wob + (size_t)(col0 + 16 * wl + 8 + lr) * 1024 + csw;
            unsigned short* lA  = sAg + wl * 512;
            unsigned short* lB0 = sBg + wl * 1024;
            unsigned short* lB1 = sBg + wl * 1024 + 512;
            int xr = (r & 7) << 4;
            int cq = (lane >> 4) << 4;
            const char* cA = (const char*)sAg;
            const char* cB = (const char*)sBg;
            int a0 = (mw + r) * 128 + (cq ^ xr);
            int a1 = (mw + r) * 128 + ((cq + 64) ^ xr);
            int b0 = (nw + r) * 128 + (cq ^ xr);
            int b1 = (nw + r) * 128 + ((cq + 64) ^ xr);

            floatx4 acc0 = {0,0,0,0}, acc1 = {0,0,0,0};
            gload16(gactx, lA); gload16(gB0, lB0); gload16(gB1, lB1);

            for (int kb = 0; kb < 16; ++kb) {
                __syncthreads();
                bf16x8 af0 = *(const bf16x8*)(cA + a0);
                bf16x8 af1 = *(const bf16x8*)(cA + a1);
                bf16x8 b00 = *(const bf16x8*)(cB + b0);
                bf16x8 b10 = *(const bf16x8*)(cB + b0 + 2048);
                bf16x8 b01 = *(const bf16x8*)(cB + b1);
                bf16x8 b11 = *(const bf16x8*)(cB + b1 + 2048);
                acc0 = __builtin_amdgcn_mfma_f32_16x16x32_bf16(af0, b00, acc0, 0, 0, 0);
                acc1 = __builtin_amdgcn_mfma_f32_16x16x32_bf16(af0, b10, acc1, 0, 0, 0);
                acc0 = __builtin_amdgcn_mfma_f32_16x16x32_bf16(af1, b01, acc0, 0, 0, 0);
                acc1 = __builtin_amdgcn_mfma_f32_16x16x32_bf16(af1, b11, acc1, 0, 0, 0);
                if (kb < 15) {
                    __syncthreads();
                    int kn = kb + 1;
                    const unsigned short* ga = (kn < 8 ? gactx : gaq) + (kn & 7) * 64;
                    gB0 += 64; gB1 += 64;
                    gload16(ga, lA); gload16(gB0, lB0); gload16(gB1, lB1);
                }
            }
            int rq = (lane >> 4) * 4;
            float* op = Out + (size_t)(row0 + mw + rq) * 512 + col0 + nw + r;
#pragma unroll
            for (int i = 0; i < 4; ++i) {
                op[(size_t)i * 512]      = ftanh(acc0[i]);
                op[(size_t)i * 512 + 16] = ftanh(acc1[i]);
            }
        }
    }
}

// ===================== FALLBACK 5-KERNEL PIPELINE (R16) ======================
__global__ __launch_bounds__(256) void cast_all_bf16(
    const float* __restrict__ q,  const float* __restrict__ e,
    const float* __restrict__ Ws, const float* __restrict__ Wh,
    const float* __restrict__ Wo,
    unsigned short* __restrict__ qb,  unsigned short* __restrict__ eb,
    unsigned short* __restrict__ Wsb, unsigned short* __restrict__ Whb,
    unsigned short* __restrict__ Wob)
{
    int blk = blockIdx.x;
    const float* src; unsigned short* dst; int base;
    if      (blk < 1024) { src = q;  dst = qb;  base = blk; }
    else if (blk < 2048) { src = e;  dst = eb;  base = blk - 1024; }
    else if (blk < 2304) { src = Ws; dst = Wsb; base = blk - 2048; }
    else if (blk < 2560) { src = Wh; dst = Whb; base = blk - 2304; }
    else                 { src = Wo; dst = Wob; base = blk - 2560; }
    size_t i = (size_t)base * 1024 + threadIdx.x * 4;
    float4 f = *(const float4*)(src + i);
    ushort4 o;
    o.x = (unsigned short)f2bf_bits(f.x);
    o.y = (unsigned short)f2bf_bits(f.y);
    o.z = (unsigned short)f2bf_bits(f.z);
    o.w = (unsigned short)f2bf_bits(f.w);
    *(ushort4*)(dst + i) = o;
}

__global__ __launch_bounds__(256) void gemm32x64_exp_dual(
    const unsigned short* __restrict__ Xa, const unsigned short* __restrict__ Wa,
    float* __restrict__ Ca,
    const unsigned short* __restrict__ Xb, const unsigned short* __restrict__ Wb_,
    float* __restrict__ Cb)
{
    __shared__ unsigned short sA[32 * 64];
    __shared__ unsigned short sB[64 * 64];
    const int K = 512;
    int blk = blockIdx.x;
    const unsigned short* X; const unsigned short* W; float* C;
    int mt, nt, N;
    if (blk < 512) { X = Xa; W = Wa; C = Ca; N = 512;  mt = blk >> 3; nt = blk & 7; }
    else { blk -= 512; X = Xb; W = Wb_; C = Cb; N = 2048; mt = blk >> 5; nt = blk & 31; }
    int row0 = mt * 32, col0 = nt * 64;
    int tid = threadIdx.x, lane = tid & 63, w = tid >> 6;
    int mw = (w & 1) * 16, nw = (w >> 1) * 32;
    int r = lane & 15;
    int lr  = lane >> 3;
    int csw = ((lane & 7) ^ lr) << 3;
    const unsigned short* gA  = X + (size_t)(row0 + 8 * w + lr) * K + csw;
    const unsigned short* gB0 = W + (size_t)(col0 + 16 * w + lr) * K + csw;
    const unsigned short* gB1 = W + (size_t)(col0 + 16 * w + 8 + lr) * K + csw;
    unsigned short* lA  = &sA[w * 512];
    unsigned short* lB0 = &sB[w * 1024];
    unsigned short* lB1 = &sB[w * 1024 + 512];
    int xr = (r & 7) << 4;
    int cq = (lane >> 4) << 4;
    const char* cA = (const char*)sA;
    const char* cB = (const char*)sB;
    int a0 = (mw + r) * 128 + (cq ^ xr);
    int a1 = (mw + r) * 128 + ((cq + 64) ^ xr);
    int b0 = (nw + r) * 128 + (cq ^ xr);
    int b1 = (nw + r) * 128 + ((cq + 64) ^ xr);

    floatx4 acc0 = {0,0,0,0}, acc1 = {0,0,0,0};
    gload16(gA, lA); gload16(gB0, lB0); gload16(gB1, lB1);

    for (int kb = 0; kb < 8; ++kb) {
        __syncthreads();
        bf16x8 af0 = *(const bf16x8*)(cA + a0);
        bf16x8 af1 = *(const bf16x8*)(cA + a1);
        bf16x8 b00 = *(const bf16x8*)(cB + b0);
        bf16x8 b10 = *(const bf16x8*)(cB + b0 + 2048);
        bf16x8 b01 = *(const bf16x8*)(cB + b1);
        bf16x8 b11 = *(const bf16x8*)(cB + b1 + 2048);
        acc0 = __builtin_amdgcn_mfma_f32_16x16x32_bf16(af0, b00, acc0, 0, 0, 0);
        acc1 = __builtin_amdgcn_mfma_f32_16x16x32_bf16(af0, b10, acc1, 0, 0, 0);
        acc0 = __builtin_amdgcn_mfma_f32_16x16x32_bf16(af1, b01, acc0, 0, 0, 0);
        acc1 = __builtin_amdgcn_mfma_f32_16x16x32_bf16(af1, b11, acc1, 0, 0, 0);
        if (kb < 7) {
            __syncthreads();
            gA += 64; gB0 += 64; gB1 += 64;
            gload16(gA, lA); gload16(gB0, lB0); gload16(gB1, lB1);
        }
    }
    int rq = (lane >> 4) * 4;
    float* cp = C + (size_t)(row0 + mw + rq) * N + col0 + nw + r;
#pragma unroll
    for (int i = 0; i < 4; ++i) {
        cp[(size_t)i * N]      = fexp2x(acc0[i]);
        cp[(size_t)i * N + 16] = fexp2x(acc1[i]);
    }
}

__global__ __launch_bounds__(512) void energies_v6(
    const float* __restrict__ EA, const float* __restrict__ EBT,
    const float* __restrict__ Vv, const int* __restrict__ Len,
    float* __restrict__ E)
{
    __shared__ float sA[TQ][516];
    __shared__ float sWn[512];
    __shared__ float sRed[8][TQ][130];

    int tid  = threadIdx.x;
    int lane = tid & 63;
    int w    = tid >> 6;
    int blk  = blockIdx.x;
    int b    = blk >> 7;
    int j    = (blk >> 6) & 1;
    int tq   = blk & 63;
    int len  = Len[b];
    if (j * 128 >= len) return;
    int row0g = b * 256 + tq * TQ;

    {
        int t = tid >> 7, c = (tid & 127) * 4;
        *(float4*)&sA[t][c] = *(const float4*)(EA + (size_t)(row0g + t) * 512 + c);
        sWn[tid] = -2.0f * Vv[tid];
    }
    __syncthreads();

    int h0 = w * 64;
    float acc[TQ][2] = {{0.f}};
    const float* bt = EBT + (size_t)h0 * 2048 + b * 256 + j * 128 + lane;

    float B[8], P[8];
#pragma unroll
    for (int i = 0; i < 4; ++i) {
        B[i]     = bt[(size_t)i * 2048];
        B[i + 4] = bt[(size_t)i * 2048 + 64];
    }
#pragma unroll
    for (int hh = 0; hh < 64; hh += 4) {
        if (hh + 4 < 64) {
            const float* nb = bt + (size_t)(hh + 4) * 2048;
#pragma unroll
            for (int i = 0; i < 4; ++i) {
                P[i]     = nb[(size_t)i * 2048];
                P[i + 4] = nb[(size_t)i * 2048 + 64];
            }
        }
        float4 w4 = *(const float4*)&sWn[h0 + hh];
#pragma unroll
        for (int t = 0; t < TQ; ++t) {
            float4 a4 = *(const float4*)&sA[t][h0 + hh];
#pragma unroll
            for (int u = 0; u < 2; ++u) {
                float d0 = fmaf(a4.x, B[4 * u + 0], 1.0f);
                float d1 = fmaf(a4.y, B[4 * u + 1], 1.0f);
                float d2 = fmaf(a4.z, B[4 * u + 2], 1.0f);
                float d3 = fmaf(a4.w, B[4 * u + 3], 1.0f);
                float num01 = fmaf(w4.x, d1, w4.y * d0);
                float num23 = fmaf(w4.z, d3, w4.w * d2);
                acc[t][u] = fmaf(num01, frcp(d0 * d1), acc[t][u]);
                acc[t][u] = fmaf(num23, frcp(d2 * d3), acc[t][u]);
            }
        }
#pragma unroll
        for (int i = 0; i < 8; ++i) B[i] = P[i];
    }

#pragma unroll
    for (int t = 0; t < TQ; ++t) {
        sRed[w][t][lane]      = acc[t][0];
        sRed[w][t][lane + 64] = acc[t][1];
    }
    __syncthreads();
    {
        int t = tid >> 7, s = tid & 127;
        float sum = 0.f;
#pragma unroll
        for (int ww = 0; ww < 8; ++ww) sum += sRed[ww][t][s];
        E[(size_t)(row0g + t) * 256 + j * 128 + s] = sum;
    }
}

__global__ __launch_bounds__(512) void softmax_ctx_fused(
    const float* __restrict__ E, const unsigned short* __restrict__ Eb,
    const int* __restrict__ Len, unsigned short* __restrict__ Ctx)
{
    __shared__ unsigned short EncT[64][264];
    __shared__ unsigned short sWb[64][264];
    int tid = threadIdx.x, lane = tid & 63, w = tid >> 6;
    int blk = blockIdx.x;
    int b = blk & 7, hq = (blk >> 3) & 7, tg = blk >> 6;
    int len = Len[b];

    {
        int s = tid >> 1, hg = (tid & 1) * 32;
        const ushort4* src = (const ushort4*)(Eb + (size_t)(b * 256 + s) * 512 + hq * 64 + hg);
#pragma unroll
        for (int k = 0; k < 8; ++k) {
            ushort4 u = src[k];
            EncT[hg + k * 4 + 0][s] = u.x;
            EncT[hg + k * 4 + 1][s] = u.y;
            EncT[hg + k * 4 + 2][s] = u.z;
            EncT[hg + k * 4 + 3][s] = u.w;
        }
    }
    for (int i = 0; i < 8; ++i) {
        int row = w * 8 + i;
        const float* erow = E + (size_t)(b * 256 + tg * 64 + row) * 256;
        float ev[4];
#pragma unroll
        for (int j = 0; j < 4; ++j) {
            int s = lane + 64 * j;
            ev[j] = (s < len) ? erow[s] : NEGBIG;
        }
        float m = fmaxf(fmaxf(ev[0], ev[1]), fmaxf(ev[2], ev[3]));
#pragma unroll
        for (int o = 1; o < 64; o <<= 1) m = fmaxf(m, __shfl_xor(m, o, 64));
        float wv[4], wsum = 0.f;
#pragma unroll
        for (int j = 0; j < 4; ++j) { wv[j] = fexp2((ev[j] - m) * LOG2E); wsum += wv[j]; }
#pragma unroll
        for (int o = 1; o < 64; o <<= 1) wsum += __shfl_xor(wsum, o, 64);
        float inv = frcp(wsum);
#pragma unroll
        for (int j = 0; j < 4; ++j)
            sWb[row][lane + 64 * j] = (unsigned short)f2bf_bits(wv[j] * inv);
    }
    __syncthreads();

    int mt = w & 3, npair = w >> 2;
    int t0 = mt * 16;
    int r  = lane & 15, kq = (lane >> 4) * 8;
    int n0 = npair * 32 + r;
    floatx4 acc0 = {0.f,0.f,0.f,0.f}, acc1 = {0.f,0.f,0.f,0.f};
#pragma unroll
    for (int k = 0; k < 8; ++k) {
        bf16x8 a  = *(const bf16x8*)(&sWb[t0 + r][kq + 32 * k]);
        bf16x8 b0 = *(const bf16x8*)(&EncT[n0][kq + 32 * k]);
        bf16x8 b1 = *(const bf16x8*)(&EncT[n0 + 16][kq + 32 * k]);
        acc0 = __builtin_amdgcn_mfma_f32_16x16x32_bf16(a, b0, acc0, 0, 0, 0);
        acc1 = __builtin_amdgcn_mfma_f32_16x16x32_bf16(a, b1, acc1, 0, 0, 0);
    }
    int row0 = (lane >> 4) * 4;
    unsigned short* op = Ctx + (size_t)(b * 256 + tg * 64 + t0 + row0) * 512 + hq * 64 + npair * 32 + r;
#pragma unroll
    for (int i = 0; i < 4; ++i) {
        op[i * 512]      = (unsigned short)f2bf_bits(acc0[i]);
        op[i * 512 + 16] = (unsigned short)f2bf_bits(acc1[i]);
    }
}

__global__ __launch_bounds__(256) void out_gemm32x64_tanh(
    const unsigned short* __restrict__ Ctx, const unsigned short* __restrict__ Q,
    const unsigned short* __restrict__ Wout, float* __restrict__ Out)
{
    __shared__ unsigned short sA[32 * 64];
    __shared__ unsigned short sB[64 * 64];
    const int N = 512, KW = 1024;
    int blk = blockIdx.x;
    int mt = blk >> 3, nt = blk & 7;
    int row0 = mt * 32, col0 = nt * 64;
    int tid = threadIdx.x, lane = tid & 63, w = tid >> 6;
    int mw = (w & 1) * 16, nw = (w >> 1) * 32;
    int r = lane & 15;
    int lr  = lane >> 3;
    int csw = ((lane & 7) ^ lr) << 3;
    const unsigned short* gactx = Ctx  + (size_t)(row0 + 8 * w + lr) * 512 + csw;
    const unsigned short* gaq   = Q    + (size_t)(row0 + 8 * w + lr) * 512 + csw;
    const unsigned short* gB0   = Wout + (size_t)(col0 + 16 * w + lr) * KW + csw;
    const unsigned short* gB1   = Wout + (size_t)(col0 + 16 * w + 8 + lr) * KW + csw;
    unsigned short* lA  = &sA[w * 512];
    unsigned short* lB0 = &sB[w * 1024];
    unsigned short* lB1 = &sB[w * 1024 + 512];
    int xr = (r & 7) << 4;
    int cq = (lane >> 4) << 4;
    const char* cA = (const char*)sA;
    const char* cB = (const char*)sB;
    int a0 = (mw + r) * 128 + (cq ^ xr);
    int a1 = (mw + r) * 128 + ((cq + 64) ^ xr);
    int b0 = (nw + r) * 128 + (cq ^ xr);
    int b1 = (nw + r) * 128 + ((cq + 64) ^ xr);

    floatx4 acc0 = {0,0,0,0}, acc1 = {0,0,0,0};
    gload16(gactx, lA); gload16(gB0, lB0); gload16(gB1, lB1);

    for (int kb = 0; kb < 16; ++kb) {
        __syncthreads();
        bf16x8 af0 = *(const bf16x8*)(cA + a0);
        bf16x8 af1 = *(const bf16x8*)(cA + a1);
        bf16x8 b00 = *(const bf16x8*)(cB + b0);
        bf16x8 b10 = *(const bf16x8*)(cB + b0 + 2048);
        bf16x8 b01 = *(const bf16x8*)(cB + b1);
        bf16x8 b11 = *(const bf16x8*)(cB + b1 + 2048);
        acc0 = __builtin_amdgcn_mfma_f32_16x16x32_bf16(af0, b00, acc0, 0, 0, 0);
        acc1 = __builtin_amdgcn_mfma_f32_16x16x32_bf16(af0, b10, acc1, 0, 0, 0);
        acc0 = __builtin_amdgcn_mfma_f32_16x16x32_bf16(af1, b01, acc0, 0, 0, 0);
        acc1 = __builtin_amdgcn_mfma_f32_16x16x32_bf16(af1, b11, acc1, 0, 0, 0);
        if (kb < 15) {
            __syncthreads();
            int kn = kb + 1;
            const unsigned short* ga = (kn < 8 ? gactx : gaq) + (kn & 7) * 64;
            gB0 += 64; gB1 += 64;
            gload16(ga, lA); gload16(gB0, lB0); gload16(gB1, lB1);
        }
    }
    int rq = (lane >> 4) * 4;
    float* op = Out + (size_t)(row0 + mw + rq) * N + col0 + nw + r;
#pragma unroll
    for (int i = 0; i < 4; ++i) {
        op[(size_t)i * N]      = ftanh(acc0[i]);
        op[(size_t)i * N + 16] = ftanh(acc1[i]);
    }
}

extern "C" void kernel_launch(void* const* d_in, const int* in_sizes, int n_in,
                              void* d_out, int out_size, void* d_ws, size_t ws_size,
                              hipStream_t stream)
{
    const float* query = (const float*)d_in[0]; // fp32 8x256x512
    const float* enc   = (const float*)d_in[1]; // fp32 8x256x512
    const int*   len   = (const int*)d_in[2];   // int32 8
    const float* Ws    = (const float*)d_in[3]; // fp32 512x512
    const float* Wh    = (const float*)d_in[4]; // fp32 512x512
    const float* v     = (const float*)d_in[5]; // fp32 512
    const float* Wout  = (const float*)d_in[6]; // fp32 512x1024
    float* out = (float*)d_out;                 // fp32 8x256x512

    float* EA   = (float*)d_ws;                                   // 4 MB [2048][512]
    float* EBT  = EA + 2048 * 512;                                // 4 MB [512][2048]
    float* E    = EBT + 512 * 2048;                               // 2 MB [2048][256]
    unsigned short* qb  = (unsigned short*)(E + 2048 * 256);      // 2 MB
    unsigned short* eb  = qb + 2048 * 512;                        // 2 MB
    unsigned short* Wsb = eb + 2048 * 512;                        // 0.5 MB
    unsigned short* Whb = Wsb + 512 * 512;                        // 0.5 MB
    unsigned short* Wob = Whb + 512 * 512;                        // 1 MB
    unsigned short* ctx = Wob + 512 * 1024;                       // 2 MB

    // cooperative grid size: residency-guaranteed (cached across calls)
    static int coopGrid = -1;
    if (coopGrid < 0) {
        int mb = 0;
        if (hipOccupancyMaxActiveBlocksPerMultiprocessor(&mb, bahdanau_mega, 512, 0)
                != hipSuccess || mb < 1)
            mb = 0;
        coopGrid = mb > 0 ? (mb * 256 > 512 ? 512 : mb * 256) : 0;
    }

    bool ok = false;
    if (coopGrid > 0) {
        void* args[] = { (void*)&query, (void*)&enc, (void*)&len, (void*)&Ws,
                         (void*)&Wh, (void*)&v, (void*)&Wout, (void*)&out,
                         (void*)&EA, (void*)&EBT, (void*)&E,
                         (void*)&qb, (void*)&eb, (void*)&Wsb, (void*)&Whb,
                         (void*)&Wob, (void*)&ctx };
        hipError_t rc = hipLaunchCooperativeKernel((const void*)bahdanau_mega,
                                                   dim3(coopGrid), dim3(512),
                                                   args, 0, stream);
        if (rc == hipSuccess) ok = true;
        else { (void)hipGetLastError(); coopGrid = 0; }  // don't retry next call
    }
    if (!ok) {   // fallback: proven R16 5-kernel pipeline
        cast_all_bf16<<<3072, 256, 0, stream>>>(query, enc, Ws, Wh, Wout,
                                                qb, eb, Wsb, Whb, Wob);
        gemm32x64_exp_dual<<<1024, 256, 0, stream>>>(qb, Wsb, EA, Whb, eb, EBT);
        energies_v6<<<1024, 512, 0, stream>>>(EA, EBT, v, len, E);
        softmax_ctx_fused<<<256, 512, 0, stream>>>(E, eb, len, ctx);
        out_gemm32x64_tanh<<<512, 256, 0, stream>>>(ctx, qb, Wob, out);
    }
}

// Round 4
// 132.402 us; speedup vs baseline: 2.1309x; 2.1309x over previous
//
#include <hip/hip_runtime.h>
#include <hip/hip_bf16.h>

// BahdanauAttention on MI355X (gfx950). ALL float I/O is fp32.
// Internal compute uses bf16 MFMA (no fp32 MFMA on CDNA4).
// Pipeline (5 launches) — R19: R16 pipeline + K2 TQ=8 / masked-u1:
//  K0: cast fp32->bf16 for query/enc/W_s/W_h/W_out into ws
//  K1: EA = exp(2*(query @ W_s^T)) [2048x512], EBT = exp(2*(enc @ Wh^T))^T
//      [512x2048]  (exp-product form: tanh(a+b)=1-2/(1+e^2a e^2b))
//      gload_lds(16B) staging, XOR-swizzled source, linear LDS (R16).
//  K2: energies E[t][s] = sum_h (-2 v_h)/(1+EA*EB). Block=(b, 8 t, 128-s grp),
//      wave=64-h slice, lane=2 s. TQ=8 halves EBT L2 re-reads (256KB/block
//      amortized over 2x t-work); block-uniform skip of the upper 64-s half
//      when len <= j*128+64 (K3 never reads E[s>=len]).
//  K3: softmax(E, len) -> LDS bf16 weights; ctx = W @ enc [MFMA, fused]
//  K4: out = tanh([ctx|query] @ W_out^T)  [32x64 LDS-tiled MFMA, concat-K]
// R15 lesson: inline fp32->bf16 casts in GEMM staging sit on the serial
// region between barriers -> dedicated cast kernel is cheaper.
// R16 lesson: gload_lds staging in K1/K4 = -1.6us (TLP already hid most).
// R17 lesson: v_pk_fma_f32 adds NO fp32 throughput on CDNA4 (157 TF peak is
// scalar-reachable; packed is code density only).
// R18 lesson: cg::grid.sync() costs ~60us/sync on MI355X (8 XCDs, device-
// scope atomics) — a 5-phase mega-kernel ran 283us with all pipes <10% busy.
// Never fuse us-scale phases behind grid-wide barriers on this chip.
// d_ws is 256 MiB; harness 0xAA fill (~45 us) is a fixed serialized cost.

typedef __attribute__((ext_vector_type(8))) short bf16x8;
typedef __attribute__((ext_vector_type(4))) float floatx4;

#define C2LOG2E 2.8853900817779268f   // 2*log2(e)
#define LOG2E   1.4426950408889634f
#define NEGBIG  -1e30f

__device__ __forceinline__ float fexp2(float x) { return __builtin_amdgcn_exp2f(x); }
__device__ __forceinline__ float frcp(float x)  { return __builtin_amdgcn_rcpf(x); }
__device__ __forceinline__ float ftanh(float x) {
    return 1.0f - 2.0f * frcp(1.0f + fexp2(C2LOG2E * x));
}
__device__ __forceinline__ float fexp2x(float x) {   // e^{2x}
    return fexp2(C2LOG2E * x);
}

__device__ __forceinline__ unsigned int f2bf_bits(float f) {
    unsigned int u = __float_as_uint(f);
    return (u + 0x7fffu + ((u >> 16) & 1u)) >> 16;   // RNE (inputs finite)
}

// async 16B global->LDS (wave-cooperative: lane i writes ldsbase + i*16)
typedef const __attribute__((address_space(1))) unsigned int* gas_u32p;
typedef __attribute__((address_space(3))) unsigned int* las_u32p;
__device__ __forceinline__ void gload16(const void* g, void* l) {
    __builtin_amdgcn_global_load_lds((gas_u32p)g, (las_u32p)l, 16, 0, 0);
}

// ---- K0: cast fp32 -> bf16. 3072 blocks x 256 thr ---------------------------
__global__ __launch_bounds__(256) void cast_all_bf16(
    const float* __restrict__ q,  const float* __restrict__ e,
    const float* __restrict__ Ws, const float* __restrict__ Wh,
    const float* __restrict__ Wo,
    unsigned short* __restrict__ qb,  unsigned short* __restrict__ eb,
    unsigned short* __restrict__ Wsb, unsigned short* __restrict__ Whb,
    unsigned short* __restrict__ Wob)
{
    int blk = blockIdx.x;
    const float* src; unsigned short* dst; int base;
    if      (blk < 1024) { src = q;  dst = qb;  base = blk; }
    else if (blk < 2048) { src = e;  dst = eb;  base = blk - 1024; }
    else if (blk < 2304) { src = Ws; dst = Wsb; base = blk - 2048; }
    else if (blk < 2560) { src = Wh; dst = Whb; base = blk - 2304; }
    else                 { src = Wo; dst = Wob; base = blk - 2560; }
    size_t i = (size_t)base * 1024 + threadIdx.x * 4;
    float4 f = *(const float4*)(src + i);
    ushort4 o;
    o.x = (unsigned short)f2bf_bits(f.x);
    o.y = (unsigned short)f2bf_bits(f.y);
    o.z = (unsigned short)f2bf_bits(f.z);
    o.w = (unsigned short)f2bf_bits(f.w);
    *(ushort4*)(dst + i) = o;
}

// ---- K1: 32x64-tile gload_lds GEMM, dual-shape: C = exp(2*(X @ W^T)) --------
// Part A (blk<512):  X=qb[2048x512],  W=Wsb[512x512],  C=EA  [2048x512]
// Part B (blk>=512): X=Whb[512x512],  W=eb[2048x512],  C=EBT [512x2048]
__global__ __launch_bounds__(256) void gemm32x64_exp_dual(
    const unsigned short* __restrict__ Xa, const unsigned short* __restrict__ Wa,
    float* __restrict__ Ca,
    const unsigned short* __restrict__ Xb, const unsigned short* __restrict__ Wb_,
    float* __restrict__ Cb)
{
    __shared__ unsigned short sA[32 * 64];   // 4 KB, linear (swizzled content)
    __shared__ unsigned short sB[64 * 64];   // 8 KB
    const int K = 512;
    int blk = blockIdx.x;
    const unsigned short* X; const unsigned short* W; float* C;
    int mt, nt, N;
    if (blk < 512) { X = Xa; W = Wa; C = Ca; N = 512;  mt = blk >> 3; nt = blk & 7; }
    else { blk -= 512; X = Xb; W = Wb_; C = Cb; N = 2048; mt = blk >> 5; nt = blk & 31; }
    int row0 = mt * 32, col0 = nt * 64;
    int tid = threadIdx.x, lane = tid & 63, w = tid >> 6;
    int mw = (w & 1) * 16, nw = (w >> 1) * 32;
    int r = lane & 15;

    // staging: wave w stages A rows 8w..8w+7 (1 call) and B rows 16w..16w+15
    // (2 calls). lane l -> row +(l>>3), col chunk ((l&7)^(l>>3))*8 shorts.
    int lr  = lane >> 3;
    int csw = ((lane & 7) ^ lr) << 3;        // swizzled col (shorts)
    const unsigned short* gA  = X + (size_t)(row0 + 8 * w + lr) * K + csw;
    const unsigned short* gB0 = W + (size_t)(col0 + 16 * w + lr) * K + csw;
    const unsigned short* gB1 = W + (size_t)(col0 + 16 * w + 8 + lr) * K + csw;
    unsigned short* lA  = &sA[w * 512];
    unsigned short* lB0 = &sB[w * 1024];
    unsigned short* lB1 = &sB[w * 1024 + 512];

    // read offsets (bytes), loop-invariant
    int xr = (r & 7) << 4;
    int cq = (lane >> 4) << 4;               // 0,16,32,48
    const char* cA = (const char*)sA;
    const char* cB = (const char*)sB;
    int a0 = (mw + r) * 128 + (cq ^ xr);
    int a1 = (mw + r) * 128 + ((cq + 64) ^ xr);
    int b0 = (nw + r) * 128 + (cq ^ xr);
    int b1 = (nw + r) * 128 + ((cq + 64) ^ xr);

    floatx4 acc0 = {0,0,0,0}, acc1 = {0,0,0,0};
    gload16(gA, lA); gload16(gB0, lB0); gload16(gB1, lB1);   // stage kb=0

    for (int kb = 0; kb < 8; ++kb) {
        __syncthreads();                     // drains vmcnt -> tile ready
        bf16x8 af0 = *(const bf16x8*)(cA + a0);
        bf16x8 af1 = *(const bf16x8*)(cA + a1);
        bf16x8 b00 = *(const bf16x8*)(cB + b0);
        bf16x8 b10 = *(const bf16x8*)(cB + b0 + 2048);
        bf16x8 b01 = *(const bf16x8*)(cB + b1);
        bf16x8 b11 = *(const bf16x8*)(cB + b1 + 2048);
        acc0 = __builtin_amdgcn_mfma_f32_16x16x32_bf16(af0, b00, acc0, 0, 0, 0);
        acc1 = __builtin_amdgcn_mfma_f32_16x16x32_bf16(af0, b10, acc1, 0, 0, 0);
        acc0 = __builtin_amdgcn_mfma_f32_16x16x32_bf16(af1, b01, acc0, 0, 0, 0);
        acc1 = __builtin_amdgcn_mfma_f32_16x16x32_bf16(af1, b11, acc1, 0, 0, 0);
        if (kb < 7) {
            __syncthreads();                 // all waves done reading
            gA += 64; gB0 += 64; gB1 += 64;
            gload16(gA, lA); gload16(gB0, lB0); gload16(gB1, lB1);
        }
    }
    int rq = (lane >> 4) * 4;
    float* cp = C + (size_t)(row0 + mw + rq) * N + col0 + nw + r;
#pragma unroll
    for (int i = 0; i < 4; ++i) {
        cp[(size_t)i * N]      = fexp2x(acc0[i]);
        cp[(size_t)i * N + 16] = fexp2x(acc1[i]);
    }
}

// ---- K2: energies. 512 blocks = (b<<6)|(j<<5)|tq, 512 thr -------------------
// Block: batch b, t-rows tq*8..+7, s-group j (128 s). Early exit: j*128>=len.
// Wave w: h-slice [w*64,w*64+64); lane: s = j*128 + lane + {0,64}.
// E(t,s) = sum_h wn_h/(1+EA*EB), wn=-2v.  A/v LDS broadcast, B pipelined.
// TQ=8 (R19): halves per-element EBT L2 traffic vs TQ=4.
// doU1 (R19): when len <= j*128+64 the s+64 half is masked downstream ->
// skip its loads+math (block-uniform branch, no divergence).
#define TQ 8
__global__ __launch_bounds__(512) void energies_v8(
    const float* __restrict__ EA,          // [2048][512] e^{2*Ws_q}
    const float* __restrict__ EBT,         // [512][2048] e^{2*Wh_e} transposed
    const float* __restrict__ Vv,          // fp32 512
    const int* __restrict__ Len,
    float* __restrict__ E)                 // fp32 [2048][256]
{
    __shared__ float sA[TQ][516];          // 16.5 KB, uniform broadcast reads
    __shared__ float sWn[512];             // 2 KB  (-2*v)
    __shared__ float sRed[8][TQ][130];     // 33.3 KB

    int tid  = threadIdx.x;
    int lane = tid & 63;
    int w    = tid >> 6;
    int blk  = blockIdx.x;
    int b    = blk >> 6;
    int j    = (blk >> 5) & 1;
    int tq   = blk & 31;                   // low bits -> XCD balance
    int len  = Len[b];
    if (j * 128 >= len) return;            // block-uniform early exit
    bool doU1 = (j * 128 + 64) < len;      // upper 64-s half needed?
    int row0g = b * 256 + tq * TQ;

    {   // stage EA rows (8 x 512 fp32) and wn
        int t = tid >> 7, c = (tid & 127) * 4;
        *(float4*)&sA[t][c]     = *(const float4*)(EA + (size_t)(row0g + t) * 512 + c);
        *(float4*)&sA[t + 4][c] = *(const float4*)(EA + (size_t)(row0g + t + 4) * 512 + c);
        sWn[tid] = -2.0f * Vv[tid];
    }
    __syncthreads();

    int h0 = w * 64;
    float acc[TQ][2];
#pragma unroll
    for (int t = 0; t < TQ; ++t) { acc[t][0] = 0.f; acc[t][1] = 0.f; }
    const float* bt = EBT + (size_t)h0 * 2048 + b * 256 + j * 128 + lane;

    // software pipeline: prefetch B for hh=0 (4 h x up-to-2 s-halves)
    float B[8] = {0}, P[8] = {0};
#pragma unroll
    for (int i = 0; i < 4; ++i) B[i] = bt[(size_t)i * 2048];
    if (doU1) {
#pragma unroll
        for (int i = 0; i < 4; ++i) B[i + 4] = bt[(size_t)i * 2048 + 64];
    }
#pragma unroll
    for (int hh = 0; hh < 64; hh += 4) {
        if (hh + 4 < 64) {                 // prefetch next iteration's B
            const float* nb = bt + (size_t)(hh + 4) * 2048;
#pragma unroll
            for (int i = 0; i < 4; ++i) P[i] = nb[(size_t)i * 2048];
            if (doU1) {
#pragma unroll
                for (int i = 0; i < 4; ++i) P[i + 4] = nb[(size_t)i * 2048 + 64];
            }
        }
        float4 w4 = *(const float4*)&sWn[h0 + hh];            // LDS broadcast
#pragma unroll
        for (int t = 0; t < TQ; ++t) {
            float4 a4 = *(const float4*)&sA[t][h0 + hh];      // LDS broadcast
            {   // u = 0 (always live)
                float d0 = fmaf(a4.x, B[0], 1.0f);
                float d1 = fmaf(a4.y, B[1], 1.0f);
                float d2 = fmaf(a4.z, B[2], 1.0f);
                float d3 = fmaf(a4.w, B[3], 1.0f);
                float num01 = fmaf(w4.x, d1, w4.y * d0);
                float num23 = fmaf(w4.z, d3, w4.w * d2);
                acc[t][0] = fmaf(num01, frcp(d0 * d1), acc[t][0]);
                acc[t][0] = fmaf(num23, frcp(d2 * d3), acc[t][0]);
            }
            if (doU1) {                    // u = 1 (masked off when len small)
                float d0 = fmaf(a4.x, B[4], 1.0f);
                float d1 = fmaf(a4.y, B[5], 1.0f);
                float d2 = fmaf(a4.z, B[6], 1.0f);
                float d3 = fmaf(a4.w, B[7], 1.0f);
                float num01 = fmaf(w4.x, d1, w4.y * d0);
                float num23 = fmaf(w4.z, d3, w4.w * d2);
                acc[t][1] = fmaf(num01, frcp(d0 * d1), acc[t][1]);
                acc[t][1] = fmaf(num23, frcp(d2 * d3), acc[t][1]);
            }
        }
#pragma unroll
        for (int i = 0; i < 8; ++i) B[i] = P[i];
    }

#pragma unroll
    for (int t = 0; t < TQ; ++t) {
        sRed[w][t][lane]      = acc[t][0];
        sRed[w][t][lane + 64] = acc[t][1];   // 0s when !doU1 (never read by K3)
    }
    __syncthreads();
    {
        int s = tid & 127;
#pragma unroll
        for (int half = 0; half < 2; ++half) {
            int t = (tid >> 7) + 4 * half;   // 512 thr x 2 passes cover 8t x 128s
            float sum = 0.f;
#pragma unroll
            for (int ww = 0; ww < 8; ++ww) sum += sRed[ww][t][s];
            E[(size_t)(row0g + t) * 256 + j * 128 + s] = sum;
        }
    }
}

// ---- K3: fused softmax + ctx GEMM. 256 blocks = (tg<<6)|(hq<<3)|b, 512 thr --
__global__ __launch_bounds__(512) void softmax_ctx_fused(
    const float* __restrict__ E,             // fp32 [2048][256]
    const unsigned short* __restrict__ Eb,   // bf16 8x256x512
    const int* __restrict__ Len,
    unsigned short* __restrict__ Ctx)        // bf16 2048x512
{
    __shared__ unsigned short EncT[64][264];
    __shared__ unsigned short sWb[64][264];
    int tid = threadIdx.x, lane = tid & 63, w = tid >> 6;
    int blk = blockIdx.x;
    int b = blk & 7, hq = (blk >> 3) & 7, tg = blk >> 6;
    int len = Len[b];

    {   // stage + transpose enc tile: thread (s, 32-h half)
        int s = tid >> 1, hg = (tid & 1) * 32;
        const ushort4* src = (const ushort4*)(Eb + (size_t)(b * 256 + s) * 512 + hq * 64 + hg);
#pragma unroll
        for (int k = 0; k < 8; ++k) {
            ushort4 u = src[k];
            EncT[hg + k * 4 + 0][s] = u.x;
            EncT[hg + k * 4 + 1][s] = u.y;
            EncT[hg + k * 4 + 2][s] = u.z;
            EncT[hg + k * 4 + 3][s] = u.w;
        }
    }
    // softmax: wave w owns rows w*8 .. w*8+7 of the 64-row tile
    for (int i = 0; i < 8; ++i) {
        int row = w * 8 + i;
        const float* erow = E + (size_t)(b * 256 + tg * 64 + row) * 256;
        float ev[4];
#pragma unroll
        for (int j = 0; j < 4; ++j) {
            int s = lane + 64 * j;
            ev[j] = (s < len) ? erow[s] : NEGBIG;
        }
        float m = fmaxf(fmaxf(ev[0], ev[1]), fmaxf(ev[2], ev[3]));
#pragma unroll
        for (int o = 1; o < 64; o <<= 1) m = fmaxf(m, __shfl_xor(m, o, 64));
        float wv[4], wsum = 0.f;
#pragma unroll
        for (int j = 0; j < 4; ++j) { wv[j] = fexp2((ev[j] - m) * LOG2E); wsum += wv[j]; }
#pragma unroll
        for (int o = 1; o < 64; o <<= 1) wsum += __shfl_xor(wsum, o, 64);
        float inv = frcp(wsum);
#pragma unroll
        for (int j = 0; j < 4; ++j)
            sWb[row][lane + 64 * j] = (unsigned short)f2bf_bits(wv[j] * inv);
    }
    __syncthreads();

    int mt = w & 3, npair = w >> 2;          // wave: 16 t x 32 h (2 n-tiles)
    int t0 = mt * 16;
    int r  = lane & 15, kq = (lane >> 4) * 8;
    int n0 = npair * 32 + r;
    floatx4 acc0 = {0.f,0.f,0.f,0.f}, acc1 = {0.f,0.f,0.f,0.f};
#pragma unroll
    for (int k = 0; k < 8; ++k) {
        bf16x8 a  = *(const bf16x8*)(&sWb[t0 + r][kq + 32 * k]);
        bf16x8 b0 = *(const bf16x8*)(&EncT[n0][kq + 32 * k]);
        bf16x8 b1 = *(const bf16x8*)(&EncT[n0 + 16][kq + 32 * k]);
        acc0 = __builtin_amdgcn_mfma_f32_16x16x32_bf16(a, b0, acc0, 0, 0, 0);
        acc1 = __builtin_amdgcn_mfma_f32_16x16x32_bf16(a, b1, acc1, 0, 0, 0);
    }
    int row0 = (lane >> 4) * 4;
    unsigned short* op = Ctx + (size_t)(b * 256 + tg * 64 + t0 + row0) * 512 + hq * 64 + npair * 32 + r;
#pragma unroll
    for (int i = 0; i < 4; ++i) {
        op[i * 512]      = (unsigned short)f2bf_bits(acc0[i]);
        op[i * 512 + 16] = (unsigned short)f2bf_bits(acc1[i]);
    }
}

// ---- K4: 32x64-tile gload_lds GEMM, concat-K: out = tanh([ctx|q] @ Wout^T) --
__global__ __launch_bounds__(256) void out_gemm32x64_tanh(
    const unsigned short* __restrict__ Ctx, const unsigned short* __restrict__ Q,
    const unsigned short* __restrict__ Wout, float* __restrict__ Out)
{
    __shared__ unsigned short sA[32 * 64];
    __shared__ unsigned short sB[64 * 64];
    const int N = 512, KW = 1024;
    int blk = blockIdx.x;
    int mt = blk >> 3, nt = blk & 7;
    int row0 = mt * 32, col0 = nt * 64;
    int tid = threadIdx.x, lane = tid & 63, w = tid >> 6;
    int mw = (w & 1) * 16, nw = (w >> 1) * 32;
    int r = lane & 15;

    int lr  = lane >> 3;
    int csw = ((lane & 7) ^ lr) << 3;
    const unsigned short* gactx = Ctx  + (size_t)(row0 + 8 * w + lr) * 512 + csw;
    const unsigned short* gaq   = Q    + (size_t)(row0 + 8 * w + lr) * 512 + csw;
    const unsigned short* gB0   = Wout + (size_t)(col0 + 16 * w + lr) * KW + csw;
    const unsigned short* gB1   = Wout + (size_t)(col0 + 16 * w + 8 + lr) * KW + csw;
    unsigned short* lA  = &sA[w * 512];
    unsigned short* lB0 = &sB[w * 1024];
    unsigned short* lB1 = &sB[w * 1024 + 512];

    int xr = (r & 7) << 4;
    int cq = (lane >> 4) << 4;
    const char* cA = (const char*)sA;
    const char* cB = (const char*)sB;
    int a0 = (mw + r) * 128 + (cq ^ xr);
    int a1 = (mw + r) * 128 + ((cq + 64) ^ xr);
    int b0 = (nw + r) * 128 + (cq ^ xr);
    int b1 = (nw + r) * 128 + ((cq + 64) ^ xr);

    floatx4 acc0 = {0,0,0,0}, acc1 = {0,0,0,0};
    gload16(gactx, lA); gload16(gB0, lB0); gload16(gB1, lB1);   // stage kb=0

    for (int kb = 0; kb < 16; ++kb) {
        __syncthreads();
        bf16x8 af0 = *(const bf16x8*)(cA + a0);
        bf16x8 af1 = *(const bf16x8*)(cA + a1);
        bf16x8 b00 = *(const bf16x8*)(cB + b0);
        bf16x8 b10 = *(const bf16x8*)(cB + b0 + 2048);
        bf16x8 b01 = *(const bf16x8*)(cB + b1);
        bf16x8 b11 = *(const bf16x8*)(cB + b1 + 2048);
        acc0 = __builtin_amdgcn_mfma_f32_16x16x32_bf16(af0, b00, acc0, 0, 0, 0);
        acc1 = __builtin_amdgcn_mfma_f32_16x16x32_bf16(af0, b10, acc1, 0, 0, 0);
        acc0 = __builtin_amdgcn_mfma_f32_16x16x32_bf16(af1, b01, acc0, 0, 0, 0);
        acc1 = __builtin_amdgcn_mfma_f32_16x16x32_bf16(af1, b11, acc1, 0, 0, 0);
        if (kb < 15) {
            __syncthreads();
            int kn = kb + 1;
            const unsigned short* ga = (kn < 8 ? gactx : gaq) + (kn & 7) * 64;
            gB0 += 64; gB1 += 64;
            gload16(ga, lA); gload16(gB0, lB0); gload16(gB1, lB1);
        }
    }
    int rq = (lane >> 4) * 4;
    float* op = Out + (size_t)(row0 + mw + rq) * N + col0 + nw + r;
#pragma unroll
    for (int i = 0; i < 4; ++i) {
        op[(size_t)i * N]      = ftanh(acc0[i]);
        op[(size_t)i * N + 16] = ftanh(acc1[i]);
    }
}

extern "C" void kernel_launch(void* const* d_in, const int* in_sizes, int n_in,
                              void* d_out, int out_size, void* d_ws, size_t ws_size,
                              hipStream_t stream)
{
    const float* query = (const float*)d_in[0]; // fp32 8x256x512
    const float* enc   = (const float*)d_in[1]; // fp32 8x256x512
    const int*   len   = (const int*)d_in[2];   // int32 8
    const float* Ws    = (const float*)d_in[3]; // fp32 512x512
    const float* Wh    = (const float*)d_in[4]; // fp32 512x512
    const float* v     = (const float*)d_in[5]; // fp32 512
    const float* Wout  = (const float*)d_in[6]; // fp32 512x1024
    float* out = (float*)d_out;                 // fp32 8x256x512

    // d_ws is 256 MiB; generous non-aliased layout (~20 MB used)
    float* EA   = (float*)d_ws;                                   // 4 MB [2048][512]
    float* EBT  = EA + 2048 * 512;                                // 4 MB [512][2048]
    float* E    = EBT + 512 * 2048;                               // 2 MB [2048][256]
    unsigned short* qb  = (unsigned short*)(E + 2048 * 256);      // 2 MB
    unsigned short* eb  = qb + 2048 * 512;                        // 2 MB
    unsigned short* Wsb = eb + 2048 * 512;                        // 0.5 MB
    unsigned short* Whb = Wsb + 512 * 512;                        // 0.5 MB
    unsigned short* Wob = Whb + 512 * 512;                        // 1 MB
    unsigned short* ctx = Wob + 512 * 1024;                       // 2 MB

    cast_all_bf16<<<3072, 256, 0, stream>>>(query, enc, Ws, Wh, Wout,
                                            qb, eb, Wsb, Whb, Wob);
    gemm32x64_exp_dual<<<1024, 256, 0, stream>>>(qb, Wsb, EA, Whb, eb, EBT);
    energies_v8<<<512, 512, 0, stream>>>(EA, EBT, v, len, E);
    softmax_ctx_fused<<<256, 512, 0, stream>>>(E, eb, len, ctx);
    out_gemm32x64_tanh<<<512, 256, 0, stream>>>(ctx, qb, Wob, out);
}

// Round 5
// 127.433 us; speedup vs baseline: 2.2139x; 1.0390x over previous
//
#include <hip/hip_runtime.h>
#include <hip/hip_bf16.h>

// BahdanauAttention on MI355X (gfx950). ALL float I/O is fp32.
// Internal compute uses bf16 MFMA (no fp32 MFMA on CDNA4).
// Pipeline (5 launches) — R20: K2 h-split for occupancy:
//  K0: cast fp32->bf16 for query/enc/W_s/W_h/W_out into ws
//  K1: EA = exp(2*(query @ W_s^T)) [2048x512], EBT = exp(2*(enc @ Wh^T))^T
//      [512x2048]  (exp-product form: tanh(a+b)=1-2/(1+e^2a e^2b))
//      gload_lds(16B) staging, XOR-swizzled source, linear LDS (R16).
//  K2: partial energies, h SPLIT across 2 blocks (hhalf sums 256 of 512 h)
//      -> E0/E1 [2048][256] each. Block=(b, j, hhalf, 4 t), wave=32-h slice,
//      lane=2 s. Grid 2048 (~1536 live) -> 4 blocks/CU = 32 waves/CU (max).
//      R19 counters proved K2 was 52us at 31% occupancy / 28% VALUBusy —
//      latency-bound at 3.6x its 14.5us VALU floor; this restores TLP.
//  K3: softmax(E0+E1, len) -> LDS bf16 weights; ctx = W @ enc [MFMA, fused]
//  K4: out = tanh([ctx|query] @ W_out^T)  [32x64 LDS-tiled MFMA, concat-K]
// R15 lesson: inline fp32->bf16 casts in GEMM staging sit on the serial
// region between barriers -> dedicated cast kernel is cheaper.
// R16 lesson: gload_lds staging in K1/K4 = -1.6us (TLP already hid most).
// R17 lesson: v_pk_fma_f32 adds NO fp32 throughput on CDNA4.
// R18 lesson: cg::grid.sync() costs ~60us/sync on MI355X — never fuse
// us-scale phases behind grid-wide barriers on this chip.
// R19 lesson: K2 is the dominant kernel (52us); TQ=8 halved the grid and
// tanked occupancy (31%). Occupancy >> per-block reuse for this kernel.
// d_ws is 256 MiB; harness 0xAA fill (~45 us) is a fixed serialized cost.

typedef __attribute__((ext_vector_type(8))) short bf16x8;
typedef __attribute__((ext_vector_type(4))) float floatx4;

#define C2LOG2E 2.8853900817779268f   // 2*log2(e)
#define LOG2E   1.4426950408889634f
#define NEGBIG  -1e30f
#define TQ 4

__device__ __forceinline__ float fexp2(float x) { return __builtin_amdgcn_exp2f(x); }
__device__ __forceinline__ float frcp(float x)  { return __builtin_amdgcn_rcpf(x); }
__device__ __forceinline__ float ftanh(float x) {
    return 1.0f - 2.0f * frcp(1.0f + fexp2(C2LOG2E * x));
}
__device__ __forceinline__ float fexp2x(float x) {   // e^{2x}
    return fexp2(C2LOG2E * x);
}

__device__ __forceinline__ unsigned int f2bf_bits(float f) {
    unsigned int u = __float_as_uint(f);
    return (u + 0x7fffu + ((u >> 16) & 1u)) >> 16;   // RNE (inputs finite)
}

// async 16B global->LDS (wave-cooperative: lane i writes ldsbase + i*16)
typedef const __attribute__((address_space(1))) unsigned int* gas_u32p;
typedef __attribute__((address_space(3))) unsigned int* las_u32p;
__device__ __forceinline__ void gload16(const void* g, void* l) {
    __builtin_amdgcn_global_load_lds((gas_u32p)g, (las_u32p)l, 16, 0, 0);
}

// ---- K0: cast fp32 -> bf16. 3072 blocks x 256 thr ---------------------------
__global__ __launch_bounds__(256) void cast_all_bf16(
    const float* __restrict__ q,  const float* __restrict__ e,
    const float* __restrict__ Ws, const float* __restrict__ Wh,
    const float* __restrict__ Wo,
    unsigned short* __restrict__ qb,  unsigned short* __restrict__ eb,
    unsigned short* __restrict__ Wsb, unsigned short* __restrict__ Whb,
    unsigned short* __restrict__ Wob)
{
    int blk = blockIdx.x;
    const float* src; unsigned short* dst; int base;
    if      (blk < 1024) { src = q;  dst = qb;  base = blk; }
    else if (blk < 2048) { src = e;  dst = eb;  base = blk - 1024; }
    else if (blk < 2304) { src = Ws; dst = Wsb; base = blk - 2048; }
    else if (blk < 2560) { src = Wh; dst = Whb; base = blk - 2304; }
    else                 { src = Wo; dst = Wob; base = blk - 2560; }
    size_t i = (size_t)base * 1024 + threadIdx.x * 4;
    float4 f = *(const float4*)(src + i);
    ushort4 o;
    o.x = (unsigned short)f2bf_bits(f.x);
    o.y = (unsigned short)f2bf_bits(f.y);
    o.z = (unsigned short)f2bf_bits(f.z);
    o.w = (unsigned short)f2bf_bits(f.w);
    *(ushort4*)(dst + i) = o;
}

// ---- K1: 32x64-tile gload_lds GEMM, dual-shape: C = exp(2*(X @ W^T)) --------
// Part A (blk<512):  X=qb[2048x512],  W=Wsb[512x512],  C=EA  [2048x512]
// Part B (blk>=512): X=Whb[512x512],  W=eb[2048x512],  C=EBT [512x2048]
__global__ __launch_bounds__(256) void gemm32x64_exp_dual(
    const unsigned short* __restrict__ Xa, const unsigned short* __restrict__ Wa,
    float* __restrict__ Ca,
    const unsigned short* __restrict__ Xb, const unsigned short* __restrict__ Wb_,
    float* __restrict__ Cb)
{
    __shared__ unsigned short sA[32 * 64];   // 4 KB, linear (swizzled content)
    __shared__ unsigned short sB[64 * 64];   // 8 KB
    const int K = 512;
    int blk = blockIdx.x;
    const unsigned short* X; const unsigned short* W; float* C;
    int mt, nt, N;
    if (blk < 512) { X = Xa; W = Wa; C = Ca; N = 512;  mt = blk >> 3; nt = blk & 7; }
    else { blk -= 512; X = Xb; W = Wb_; C = Cb; N = 2048; mt = blk >> 5; nt = blk & 31; }
    int row0 = mt * 32, col0 = nt * 64;
    int tid = threadIdx.x, lane = tid & 63, w = tid >> 6;
    int mw = (w & 1) * 16, nw = (w >> 1) * 32;
    int r = lane & 15;

    // staging: wave w stages A rows 8w..8w+7 (1 call) and B rows 16w..16w+15
    // (2 calls). lane l -> row +(l>>3), col chunk ((l&7)^(l>>3))*8 shorts.
    int lr  = lane >> 3;
    int csw = ((lane & 7) ^ lr) << 3;        // swizzled col (shorts)
    const unsigned short* gA  = X + (size_t)(row0 + 8 * w + lr) * K + csw;
    const unsigned short* gB0 = W + (size_t)(col0 + 16 * w + lr) * K + csw;
    const unsigned short* gB1 = W + (size_t)(col0 + 16 * w + 8 + lr) * K + csw;
    unsigned short* lA  = &sA[w * 512];
    unsigned short* lB0 = &sB[w * 1024];
    unsigned short* lB1 = &sB[w * 1024 + 512];

    // read offsets (bytes), loop-invariant
    int xr = (r & 7) << 4;
    int cq = (lane >> 4) << 4;               // 0,16,32,48
    const char* cA = (const char*)sA;
    const char* cB = (const char*)sB;
    int a0 = (mw + r) * 128 + (cq ^ xr);
    int a1 = (mw + r) * 128 + ((cq + 64) ^ xr);
    int b0 = (nw + r) * 128 + (cq ^ xr);
    int b1 = (nw + r) * 128 + ((cq + 64) ^ xr);

    floatx4 acc0 = {0,0,0,0}, acc1 = {0,0,0,0};
    gload16(gA, lA); gload16(gB0, lB0); gload16(gB1, lB1);   // stage kb=0

    for (int kb = 0; kb < 8; ++kb) {
        __syncthreads();                     // drains vmcnt -> tile ready
        bf16x8 af0 = *(const bf16x8*)(cA + a0);
        bf16x8 af1 = *(const bf16x8*)(cA + a1);
        bf16x8 b00 = *(const bf16x8*)(cB + b0);
        bf16x8 b10 = *(const bf16x8*)(cB + b0 + 2048);
        bf16x8 b01 = *(const bf16x8*)(cB + b1);
        bf16x8 b11 = *(const bf16x8*)(cB + b1 + 2048);
        acc0 = __builtin_amdgcn_mfma_f32_16x16x32_bf16(af0, b00, acc0, 0, 0, 0);
        acc1 = __builtin_amdgcn_mfma_f32_16x16x32_bf16(af0, b10, acc1, 0, 0, 0);
        acc0 = __builtin_amdgcn_mfma_f32_16x16x32_bf16(af1, b01, acc0, 0, 0, 0);
        acc1 = __builtin_amdgcn_mfma_f32_16x16x32_bf16(af1, b11, acc1, 0, 0, 0);
        if (kb < 7) {
            __syncthreads();                 // all waves done reading
            gA += 64; gB0 += 64; gB1 += 64;
            gload16(gA, lA); gload16(gB0, lB0); gload16(gB1, lB1);
        }
    }
    int rq = (lane >> 4) * 4;
    float* cp = C + (size_t)(row0 + mw + rq) * N + col0 + nw + r;
#pragma unroll
    for (int i = 0; i < 4; ++i) {
        cp[(size_t)i * N]      = fexp2x(acc0[i]);
        cp[(size_t)i * N + 16] = fexp2x(acc1[i]);
    }
}

// ---- K2: partial energies. 2048 blocks = (b<<8)|(j<<7)|(hf<<6)|tq, 512 thr --
// Block: batch b, t-rows tq*4..+3, s-group j (128 s), h-half hf (256 h).
// Early exit: j*128>=len. Wave w: 32-h slice within the half; lane: 2 s.
// Epart(t,s) = sum_{h in half} wn_h/(1+EA*EB), wn=-2v. E = E0+E1 (in K3).
// A/v LDS broadcast, B 1-deep pipelined; doU1 skips masked upper 64-s half.
__global__ __launch_bounds__(512) void energies_v9(
    const float* __restrict__ EA,          // [2048][512] e^{2*Ws_q}
    const float* __restrict__ EBT,         // [512][2048] e^{2*Wh_e} transposed
    const float* __restrict__ Vv,          // fp32 512
    const int* __restrict__ Len,
    float* __restrict__ E0,                // fp32 [2048][256] partial (h<256)
    float* __restrict__ E1)                // fp32 [2048][256] partial (h>=256)
{
    __shared__ float sA[TQ][260];          // 4.1 KB (h-half of EA rows)
    __shared__ float sWn[256];             // 1 KB  (-2*v, h-half)
    __shared__ float sRed[8][TQ][130];     // 16.6 KB

    int tid  = threadIdx.x;
    int lane = tid & 63;
    int w    = tid >> 6;
    int blk  = blockIdx.x;
    int b    = blk >> 8;
    int j    = (blk >> 7) & 1;
    int hf   = (blk >> 6) & 1;
    int tq   = blk & 63;                   // low bits -> XCD balance
    int len  = Len[b];
    if (j * 128 >= len) return;            // block-uniform early exit
    bool doU1 = (j * 128 + 64) < len;      // upper 64-s half needed?
    int row0g = b * 256 + tq * TQ;

    {   // stage EA rows (4 x 256 fp32, this h-half) and wn
        int t = tid >> 7, c = (tid & 127) * 2;
        *(float2*)&sA[t][c] = *(const float2*)(EA + (size_t)(row0g + t) * 512 + hf * 256 + c);
        if (tid < 256) sWn[tid] = -2.0f * Vv[hf * 256 + tid];
    }
    __syncthreads();

    int h0 = w * 32;                       // local h-slice within the half
    float acc[TQ][2];
#pragma unroll
    for (int t = 0; t < TQ; ++t) { acc[t][0] = 0.f; acc[t][1] = 0.f; }
    const float* bt = EBT + (size_t)(hf * 256 + h0) * 2048 + b * 256 + j * 128 + lane;

    // software pipeline: prefetch B for hh=0 (4 h x up-to-2 s-halves)
    float B[8] = {0}, P[8] = {0};
#pragma unroll
    for (int i = 0; i < 4; ++i) B[i] = bt[(size_t)i * 2048];
    if (doU1) {
#pragma unroll
        for (int i = 0; i < 4; ++i) B[i + 4] = bt[(size_t)i * 2048 + 64];
    }
#pragma unroll
    for (int hh = 0; hh < 32; hh += 4) {
        if (hh + 4 < 32) {                 // prefetch next iteration's B
            const float* nb = bt + (size_t)(hh + 4) * 2048;
#pragma unroll
            for (int i = 0; i < 4; ++i) P[i] = nb[(size_t)i * 2048];
            if (doU1) {
#pragma unroll
                for (int i = 0; i < 4; ++i) P[i + 4] = nb[(size_t)i * 2048 + 64];
            }
        }
        float4 w4 = *(const float4*)&sWn[h0 + hh];            // LDS broadcast
#pragma unroll
        for (int t = 0; t < TQ; ++t) {
            float4 a4 = *(const float4*)&sA[t][h0 + hh];      // LDS broadcast
            {   // u = 0 (always live)
                float d0 = fmaf(a4.x, B[0], 1.0f);
                float d1 = fmaf(a4.y, B[1], 1.0f);
                float d2 = fmaf(a4.z, B[2], 1.0f);
                float d3 = fmaf(a4.w, B[3], 1.0f);
                float num01 = fmaf(w4.x, d1, w4.y * d0);
                float num23 = fmaf(w4.z, d3, w4.w * d2);
                acc[t][0] = fmaf(num01, frcp(d0 * d1), acc[t][0]);
                acc[t][0] = fmaf(num23, frcp(d2 * d3), acc[t][0]);
            }
            if (doU1) {                    // u = 1 (masked off when len small)
                float d0 = fmaf(a4.x, B[4], 1.0f);
                float d1 = fmaf(a4.y, B[5], 1.0f);
                float d2 = fmaf(a4.z, B[6], 1.0f);
                float d3 = fmaf(a4.w, B[7], 1.0f);
                float num01 = fmaf(w4.x, d1, w4.y * d0);
                float num23 = fmaf(w4.z, d3, w4.w * d2);
                acc[t][1] = fmaf(num01, frcp(d0 * d1), acc[t][1]);
                acc[t][1] = fmaf(num23, frcp(d2 * d3), acc[t][1]);
            }
        }
#pragma unroll
        for (int i = 0; i < 8; ++i) B[i] = P[i];
    }

#pragma unroll
    for (int t = 0; t < TQ; ++t) {
        sRed[w][t][lane]      = acc[t][0];
        sRed[w][t][lane + 64] = acc[t][1];   // 0s when !doU1 (never read by K3)
    }
    __syncthreads();
    {
        int t = tid >> 7, s = tid & 127;   // 512 thr cover 4t x 128s
        float sum = 0.f;
#pragma unroll
        for (int ww = 0; ww < 8; ++ww) sum += sRed[ww][t][s];
        float* Ep = hf ? E1 : E0;
        Ep[(size_t)(row0g + t) * 256 + j * 128 + s] = sum;
    }
}

// ---- K3: fused softmax + ctx GEMM. 256 blocks = (tg<<6)|(hq<<3)|b, 512 thr --
__global__ __launch_bounds__(512) void softmax_ctx_fused(
    const float* __restrict__ E0,            // fp32 [2048][256] h<256 partial
    const float* __restrict__ E1,            // fp32 [2048][256] h>=256 partial
    const unsigned short* __restrict__ Eb,   // bf16 8x256x512
    const int* __restrict__ Len,
    unsigned short* __restrict__ Ctx)        // bf16 2048x512
{
    __shared__ unsigned short EncT[64][264];
    __shared__ unsigned short sWb[64][264];
    int tid = threadIdx.x, lane = tid & 63, w = tid >> 6;
    int blk = blockIdx.x;
    int b = blk & 7, hq = (blk >> 3) & 7, tg = blk >> 6;
    int len = Len[b];

    {   // stage + transpose enc tile: thread (s, 32-h half)
        int s = tid >> 1, hg = (tid & 1) * 32;
        const ushort4* src = (const ushort4*)(Eb + (size_t)(b * 256 + s) * 512 + hq * 64 + hg);
#pragma unroll
        for (int k = 0; k < 8; ++k) {
            ushort4 u = src[k];
            EncT[hg + k * 4 + 0][s] = u.x;
            EncT[hg + k * 4 + 1][s] = u.y;
            EncT[hg + k * 4 + 2][s] = u.z;
            EncT[hg + k * 4 + 3][s] = u.w;
        }
    }
    // softmax: wave w owns rows w*8 .. w*8+7 of the 64-row tile
    for (int i = 0; i < 8; ++i) {
        int row = w * 8 + i;
        size_t ro = (size_t)(b * 256 + tg * 64 + row) * 256;
        const float* er0 = E0 + ro;
        const float* er1 = E1 + ro;
        float ev[4];
#pragma unroll
        for (int j = 0; j < 4; ++j) {
            int s = lane + 64 * j;
            ev[j] = (s < len) ? (er0[s] + er1[s]) : NEGBIG;
        }
        float m = fmaxf(fmaxf(ev[0], ev[1]), fmaxf(ev[2], ev[3]));
#pragma unroll
        for (int o = 1; o < 64; o <<= 1) m = fmaxf(m, __shfl_xor(m, o, 64));
        float wv[4], wsum = 0.f;
#pragma unroll
        for (int j = 0; j < 4; ++j) { wv[j] = fexp2((ev[j] - m) * LOG2E); wsum += wv[j]; }
#pragma unroll
        for (int o = 1; o < 64; o <<= 1) wsum += __shfl_xor(wsum, o, 64);
        float inv = frcp(wsum);
#pragma unroll
        for (int j = 0; j < 4; ++j)
            sWb[row][lane + 64 * j] = (unsigned short)f2bf_bits(wv[j] * inv);
    }
    __syncthreads();

    int mt = w & 3, npair = w >> 2;          // wave: 16 t x 32 h (2 n-tiles)
    int t0 = mt * 16;
    int r  = lane & 15, kq = (lane >> 4) * 8;
    int n0 = npair * 32 + r;
    floatx4 acc0 = {0.f,0.f,0.f,0.f}, acc1 = {0.f,0.f,0.f,0.f};
#pragma unroll
    for (int k = 0; k < 8; ++k) {
        bf16x8 a  = *(const bf16x8*)(&sWb[t0 + r][kq + 32 * k]);
        bf16x8 b0 = *(const bf16x8*)(&EncT[n0][kq + 32 * k]);
        bf16x8 b1 = *(const bf16x8*)(&EncT[n0 + 16][kq + 32 * k]);
        acc0 = __builtin_amdgcn_mfma_f32_16x16x32_bf16(a, b0, acc0, 0, 0, 0);
        acc1 = __builtin_amdgcn_mfma_f32_16x16x32_bf16(a, b1, acc1, 0, 0, 0);
    }
    int row0 = (lane >> 4) * 4;
    unsigned short* op = Ctx + (size_t)(b * 256 + tg * 64 + t0 + row0) * 512 + hq * 64 + npair * 32 + r;
#pragma unroll
    for (int i = 0; i < 4; ++i) {
        op[i * 512]      = (unsigned short)f2bf_bits(acc0[i]);
        op[i * 512 + 16] = (unsigned short)f2bf_bits(acc1[i]);
    }
}

// ---- K4: 32x64-tile gload_lds GEMM, concat-K: out = tanh([ctx|q] @ Wout^T) --
__global__ __launch_bounds__(256) void out_gemm32x64_tanh(
    const unsigned short* __restrict__ Ctx, const unsigned short* __restrict__ Q,
    const unsigned short* __restrict__ Wout, float* __restrict__ Out)
{
    __shared__ unsigned short sA[32 * 64];
    __shared__ unsigned short sB[64 * 64];
    const int N = 512, KW = 1024;
    int blk = blockIdx.x;
    int mt = blk >> 3, nt = blk & 7;
    int row0 = mt * 32, col0 = nt * 64;
    int tid = threadIdx.x, lane = tid & 63, w = tid >> 6;
    int mw = (w & 1) * 16, nw = (w >> 1) * 32;
    int r = lane & 15;

    int lr  = lane >> 3;
    int csw = ((lane & 7) ^ lr) << 3;
    const unsigned short* gactx = Ctx  + (size_t)(row0 + 8 * w + lr) * 512 + csw;
    const unsigned short* gaq   = Q    + (size_t)(row0 + 8 * w + lr) * 512 + csw;
    const unsigned short* gB0   = Wout + (size_t)(col0 + 16 * w + lr) * KW + csw;
    const unsigned short* gB1   = Wout + (size_t)(col0 + 16 * w + 8 + lr) * KW + csw;
    unsigned short* lA  = &sA[w * 512];
    unsigned short* lB0 = &sB[w * 1024];
    unsigned short* lB1 = &sB[w * 1024 + 512];

    int xr = (r & 7) << 4;
    int cq = (lane >> 4) << 4;
    const char* cA = (const char*)sA;
    const char* cB = (const char*)sB;
    int a0 = (mw + r) * 128 + (cq ^ xr);
    int a1 = (mw + r) * 128 + ((cq + 64) ^ xr);
    int b0 = (nw + r) * 128 + (cq ^ xr);
    int b1 = (nw + r) * 128 + ((cq + 64) ^ xr);

    floatx4 acc0 = {0,0,0,0}, acc1 = {0,0,0,0};
    gload16(gactx, lA); gload16(gB0, lB0); gload16(gB1, lB1);   // stage kb=0

    for (int kb = 0; kb < 16; ++kb) {
        __syncthreads();
        bf16x8 af0 = *(const bf16x8*)(cA + a0);
        bf16x8 af1 = *(const bf16x8*)(cA + a1);
        bf16x8 b00 = *(const bf16x8*)(cB + b0);
        bf16x8 b10 = *(const bf16x8*)(cB + b0 + 2048);
        bf16x8 b01 = *(const bf16x8*)(cB + b1);
        bf16x8 b11 = *(const bf16x8*)(cB + b1 + 2048);
        acc0 = __builtin_amdgcn_mfma_f32_16x16x32_bf16(af0, b00, acc0, 0, 0, 0);
        acc1 = __builtin_amdgcn_mfma_f32_16x16x32_bf16(af0, b10, acc1, 0, 0, 0);
        acc0 = __builtin_amdgcn_mfma_f32_16x16x32_bf16(af1, b01, acc0, 0, 0, 0);
        acc1 = __builtin_amdgcn_mfma_f32_16x16x32_bf16(af1, b11, acc1, 0, 0, 0);
        if (kb < 15) {
            __syncthreads();
            int kn = kb + 1;
            const unsigned short* ga = (kn < 8 ? gactx : gaq) + (kn & 7) * 64;
            gB0 += 64; gB1 += 64;
            gload16(ga, lA); gload16(gB0, lB0); gload16(gB1, lB1);
        }
    }
    int rq = (lane >> 4) * 4;
    float* op = Out + (size_t)(row0 + mw + rq) * N + col0 + nw + r;
#pragma unroll
    for (int i = 0; i < 4; ++i) {
        op[(size_t)i * N]      = ftanh(acc0[i]);
        op[(size_t)i * N + 16] = ftanh(acc1[i]);
    }
}

extern "C" void kernel_launch(void* const* d_in, const int* in_sizes, int n_in,
                              void* d_out, int out_size, void* d_ws, size_t ws_size,
                              hipStream_t stream)
{
    const float* query = (const float*)d_in[0]; // fp32 8x256x512
    const float* enc   = (const float*)d_in[1]; // fp32 8x256x512
    const int*   len   = (const int*)d_in[2];   // int32 8
    const float* Ws    = (const float*)d_in[3]; // fp32 512x512
    const float* Wh    = (const float*)d_in[4]; // fp32 512x512
    const float* v     = (const float*)d_in[5]; // fp32 512
    const float* Wout  = (const float*)d_in[6]; // fp32 512x1024
    float* out = (float*)d_out;                 // fp32 8x256x512

    // d_ws is 256 MiB; generous non-aliased layout (~22 MB used)
    float* EA   = (float*)d_ws;                                   // 4 MB [2048][512]
    float* EBT  = EA + 2048 * 512;                                // 4 MB [512][2048]
    float* E0   = EBT + 512 * 2048;                               // 2 MB [2048][256]
    float* E1   = E0 + 2048 * 256;                                // 2 MB [2048][256]
    unsigned short* qb  = (unsigned short*)(E1 + 2048 * 256);     // 2 MB
    unsigned short* eb  = qb + 2048 * 512;                        // 2 MB
    unsigned short* Wsb = eb + 2048 * 512;                        // 0.5 MB
    unsigned short* Whb = Wsb + 512 * 512;                        // 0.5 MB
    unsigned short* Wob = Whb + 512 * 512;                        // 1 MB
    unsigned short* ctx = Wob + 512 * 1024;                       // 2 MB

    cast_all_bf16<<<3072, 256, 0, stream>>>(query, enc, Ws, Wh, Wout,
                                            qb, eb, Wsb, Whb, Wob);
    gemm32x64_exp_dual<<<1024, 256, 0, stream>>>(qb, Wsb, EA, Whb, eb, EBT);
    energies_v9<<<2048, 512, 0, stream>>>(EA, EBT, v, len, E0, E1);
    softmax_ctx_fused<<<256, 512, 0, stream>>>(E0, E1, eb, len, ctx);
    out_gemm32x64_tanh<<<512, 256, 0, stream>>>(ctx, qb, Wob, out);
}